// Round 13
// baseline (181.146 us; speedup 1.0000x reference)
//
#include <hip/hip_runtime.h>
#include <hip/hip_bf16.h>

#define BB   256
#define NIN  1152
#define OO   10
#define IL   8
#define OL   16
#define ROW  (OO*OL)      // 160
#define EPSQ 1e-7f
#define NT   4            // n-tile per build block
#define BT   32           // b-tile per build block

typedef unsigned short ushx8 __attribute__((ext_vector_type(8)));

__device__ __forceinline__ float bf2f(unsigned short h) {
    unsigned u = ((unsigned)h) << 16;
    return __builtin_bit_cast(float, u);
}

// K1: build u_hat[b][n][o*16+k] in bf16. NT=4 variant of the verified round-8
// kernel: LDS 24.6 KB -> 6 blocks/CU (round 8: 49 KB -> 3 blocks, 7.5 waves/CU
// was the limiter). Same o-parity swizzle + read pattern (measured 0 conflicts).
// Block 160 thr = 4 nl x 2 hh (16-b half) x 20 (o,k8) lanes. Grid (288, 8).
__global__ __launch_bounds__(160) void caps_build(
    const float* __restrict__ x, const float* __restrict__ w,
    unsigned short* __restrict__ u)
{
    __shared__ float4 wl4[NT][321];     // 320 float4 per n + 1 pad
    __shared__ float4 xl4[BT * 8];      // 32 b x (4n*8f = 8 float4)
    const int t  = threadIdx.x;
    const int n0 = blockIdx.x * NT;
    const int b0 = blockIdx.y * BT;

    // stage w (o-parity swizzle), coalesced
    const float4* wg = reinterpret_cast<const float4*>(w) + (size_t)n0 * 320;
    #pragma unroll
    for (int jj = 0; jj < 8; ++jj) {
        const int j   = t + jj * 160;        // 0..1279
        const int row = j / 320;
        const int lin = j - row * 320;
        const int o   = lin >> 5;
        const int rem = lin & 31;
        const int i   = rem >> 2;
        const int kh  = rem & 3;
        wl4[row][(o << 5) | ((i ^ (o & 1)) << 2) | kh] = wg[j];
    }
    // stage x (linear, coalesced): 256 float4
    const float4* xg = reinterpret_cast<const float4*>(x);
    {
        int j = t;
        xl4[j] = xg[((size_t)(b0 + (j >> 3)) * NIN + n0) * 2 + (j & 7)];
        j = t + 160;
        if (j < BT * 8)
            xl4[j] = xg[((size_t)(b0 + (j >> 3)) * NIN + n0) * 2 + (j & 7)];
    }
    __syncthreads();

    const int nl = t / 40;              // 0..3
    const int r  = t - nl * 40;
    const int hh = r / 20;              // 0..1: which 16-b half
    const int s  = r - hh * 20;         // 0..19
    const int o  = s >> 1;
    const int k8 = s & 1;
    const int p  = o & 1;
    const float4* wbase = &wl4[nl][(o << 5) | (k8 << 1)];
    const float4* xbase = &xl4[(hh * 16) * 8 + nl * 2];
    unsigned short* ub = u + ((size_t)(b0 + hh * 16) * NIN + n0 + nl) * ROW
                           + o * OL + k8 * 8;
    const size_t ustride = (size_t)NIN * ROW;

    for (int bl = 0; bl < 16; bl += 4) {
        float xv[4][IL];
        #pragma unroll
        for (int bb = 0; bb < 4; ++bb) {
            const float4 x0 = xbase[(bl + bb) * 8];
            const float4 x1 = xbase[(bl + bb) * 8 + 1];
            xv[bb][0] = x0.x; xv[bb][1] = x0.y; xv[bb][2] = x0.z; xv[bb][3] = x0.w;
            xv[bb][4] = x1.x; xv[bb][5] = x1.y; xv[bb][6] = x1.z; xv[bb][7] = x1.w;
        }

        float acc[4][8];
        #pragma unroll
        for (int bb = 0; bb < 4; ++bb)
            #pragma unroll
            for (int j = 0; j < 8; ++j) acc[bb][j] = 0.f;

        #pragma unroll
        for (int i = 0; i < IL; ++i) {
            const float4 wlo = wbase[(i ^ p) << 2];
            const float4 whi = wbase[((i ^ p) << 2) | 1];
            const float wv[8] = {wlo.x, wlo.y, wlo.z, wlo.w, whi.x, whi.y, whi.z, whi.w};
            #pragma unroll
            for (int bb = 0; bb < 4; ++bb)
                #pragma unroll
                for (int j = 0; j < 8; ++j)
                    acc[bb][j] = fmaf(wv[j], xv[bb][i], acc[bb][j]);
        }

        #pragma unroll
        for (int bb = 0; bb < 4; ++bb) {
            union { ushx8 v; __hip_bfloat162 h[4]; } pk;
            #pragma unroll
            for (int j = 0; j < 4; ++j)
                pk.h[j] = __float22bfloat162_rn(make_float2(acc[bb][2*j], acc[bb][2*j+1]));
            *reinterpret_cast<ushx8*>(ub + (size_t)(bl + bb) * ustride) = pk.v;
        }
    }
}

// K2: all 3 routing iterations fused, one block per b. 768 thr = 12 waves =
// 192 4-lane groups x 6 m-steps (verified round-8 structure, 80 VGPR, no
// spill). NEW: depth-1 register prefetch of the next m-step's u (packed
// ushx8, +20 VGPR) — round-8's loads were issued at loop head and consumed
// immediately, exposing L3 latency every step (VALUBusy 26%).
__global__ __launch_bounds__(768) void caps_route3(
    const unsigned short* __restrict__ u, const float* __restrict__ bias,
    float* __restrict__ outv)
{
    __shared__ float lds[12][ROW];
    __shared__ float vbuf[ROW];
    const int t  = threadIdx.x;
    const int q  = t & 3;
    const int g  = t >> 2;     // 0..191
    const int wv = t >> 6;     // 0..11
    const int b  = blockIdx.x;
    const unsigned short* ub = u + (size_t)b * NIN * ROW;

    float bsv = 0.f;
    if (t < ROW) bsv = bias[t];
    float vprev = 0.f;

    #pragma unroll
    for (int iter = 0; iter < 3; ++iter) {
        float sp[5][8];
        #pragma unroll
        for (int j = 0; j < 5; ++j)
            #pragma unroll
            for (int e = 0; e < 8; ++e) sp[j][e] = 0.f;

        ushx8 raw[5], nxt[5];
        {
            const unsigned short* un0 = ub + (size_t)g * ROW;
            #pragma unroll
            for (int j = 0; j < 5; ++j)
                raw[j] = *reinterpret_cast<const ushx8*>(un0 + (q + 4 * j) * 8);
        }

        if (iter == 0) {
            #pragma unroll
            for (int m = 0; m < 6; ++m) {
                if (m < 5) {
                    const unsigned short* un = ub + (size_t)(g + (m + 1) * 192) * ROW;
                    #pragma unroll
                    for (int j = 0; j < 5; ++j)
                        nxt[j] = *reinterpret_cast<const ushx8*>(un + (q + 4 * j) * 8);
                }
                #pragma unroll
                for (int j = 0; j < 5; ++j)
                    #pragma unroll
                    for (int e = 0; e < 8; ++e) sp[j][e] += bf2f(raw[j][e]);
                if (m < 5) {
                    #pragma unroll
                    for (int j = 0; j < 5; ++j) raw[j] = nxt[j];
                }
            }
        } else {
            float vs[5][8];
            #pragma unroll
            for (int j = 0; j < 5; ++j) {
                #pragma unroll
                for (int e = 0; e < 8; ++e) vs[j][e] = vbuf[(q + 4 * j) * 8 + e];
            }

            #pragma unroll
            for (int m = 0; m < 6; ++m) {
                if (m < 5) {
                    const unsigned short* un = ub + (size_t)(g + (m + 1) * 192) * ROW;
                    #pragma unroll
                    for (int j = 0; j < 5; ++j)
                        nxt[j] = *reinterpret_cast<const ushx8*>(un + (q + 4 * j) * 8);
                }

                float uf[5][8];
                #pragma unroll
                for (int j = 0; j < 5; ++j)
                    #pragma unroll
                    for (int e = 0; e < 8; ++e) uf[j][e] = bf2f(raw[j][e]);

                // own-parity dots (half-k), combine halves, then swap parity
                float d[5], dd[5];
                #pragma unroll
                for (int j = 0; j < 5; ++j) {
                    float acc = uf[j][0] * vs[j][0];
                    #pragma unroll
                    for (int e = 1; e < 8; ++e) acc = fmaf(uf[j][e], vs[j][e], acc);
                    acc += __shfl_xor(acc, 1, 4);   // h=0 + h=1 -> full 16-k dot
                    d[j] = acc;
                }
                #pragma unroll
                for (int j = 0; j < 5; ++j) dd[j] = __shfl_xor(d[j], 2, 4);

                float mx = fmaxf(d[0], dd[0]);
                #pragma unroll
                for (int j = 1; j < 5; ++j) mx = fmaxf(mx, fmaxf(d[j], dd[j]));
                float se = 0.f, e_[5];
                #pragma unroll
                for (int j = 0; j < 5; ++j) {
                    e_[j] = __expf(d[j] - mx);
                    se += e_[j] + __expf(dd[j] - mx);
                }
                const float rinv = 1.f / se;
                #pragma unroll
                for (int j = 0; j < 5; ++j) {
                    const float c = e_[j] * rinv;
                    #pragma unroll
                    for (int e = 0; e < 8; ++e)
                        sp[j][e] = fmaf(c, uf[j][e], sp[j][e]);
                }

                if (m < 5) {
                    #pragma unroll
                    for (int j = 0; j < 5; ++j) raw[j] = nxt[j];
                }
            }
        }

        // butterfly over the 16 groups of each wave (masks preserve q)
        #pragma unroll
        for (int j = 0; j < 5; ++j)
            #pragma unroll
            for (int e = 0; e < 8; ++e) {
                #pragma unroll
                for (int msk = 4; msk <= 32; msk <<= 1)
                    sp[j][e] += __shfl_xor(sp[j][e], msk);
            }
        if ((t & 63) < 4) {
            #pragma unroll
            for (int j = 0; j < 5; ++j)
                #pragma unroll
                for (int e = 0; e < 8; ++e)
                    lds[wv][(q + 4 * j) * 8 + e] = sp[j][e];
        }
        __syncthreads();

        if (t < ROW) {
            float ssum = 0.f;
            #pragma unroll
            for (int wvi = 0; wvi < 12; ++wvi) ssum += lds[wvi][t];
            const float sv = (iter == 0 ? 0.1f : 1.0f) * ssum + bsv;

            float dq = sv * sv;
            dq += __shfl_xor(dq, 1, 16);
            dq += __shfl_xor(dq, 2, 16);
            dq += __shfl_xor(dq, 4, 16);
            dq += __shfl_xor(dq, 8, 16);
            const float f = dq / ((1.f + dq) * sqrtf(dq + EPSQ));
            const float v = f * sv;

            if (iter == 0) { vbuf[t] = v; vprev = v; }
            else if (iter == 1) { vbuf[t] = v + vprev; }
            else { outv[(size_t)b * ROW + t] = v; }
        }
        __syncthreads();
    }
}

extern "C" void kernel_launch(void* const* d_in, const int* in_sizes, int n_in,
                              void* d_out, int out_size, void* d_ws, size_t ws_size,
                              hipStream_t stream) {
    const float* x    = (const float*)d_in[0]; // (B, NIN, 8, 1)
    const float* w    = (const float*)d_in[1]; // (1, NIN, O, 8, 16)
    const float* bias = (const float*)d_in[2]; // (1, 1, O, 16, 1)
    float* out = (float*)d_out;                // (B, 1, O, 16, 1)

    unsigned short* u = (unsigned short*)d_ws; // BB*NIN*ROW bf16 = 94.4 MB

    caps_build<<<dim3(NIN / NT, BB / BT), 160, 0, stream>>>(x, w, u);
    caps_route3<<<BB, 768, 0, stream>>>(u, bias, out);
}

// Round 14
// 78.735 us; speedup vs baseline: 2.3007x; 2.3007x over previous
//
#include <hip/hip_runtime.h>
#include <hip/hip_bf16.h>

#define BB   256
#define NIN  1152
#define OO   10
#define IL   8
#define OL   16
#define ROW  (OO*OL)      // 160
#define EPSQ 1e-7f
#define NT   4            // n-tile per build block
#define BT   32           // b-tile per build block

typedef unsigned short ushx8 __attribute__((ext_vector_type(8)));

__device__ __forceinline__ float bf2f(unsigned short h) {
    unsigned u = ((unsigned)h) << 16;
    return __builtin_bit_cast(float, u);
}

// K1: build u_hat[b][n][o*16+k] in bf16. NT=4 (verified round 13, ~8-10us):
// LDS 24.6 KB -> 6 blocks/CU, 15 waves/CU. o-parity swizzle, 0 conflicts.
// Block 160 thr = 4 nl x 2 hh (16-b half) x 20 (o,k8) lanes. Grid (288, 8).
__global__ __launch_bounds__(160) void caps_build(
    const float* __restrict__ x, const float* __restrict__ w,
    unsigned short* __restrict__ u)
{
    __shared__ float4 wl4[NT][321];     // 320 float4 per n + 1 pad
    __shared__ float4 xl4[BT * 8];      // 32 b x (4n*8f = 8 float4)
    const int t  = threadIdx.x;
    const int n0 = blockIdx.x * NT;
    const int b0 = blockIdx.y * BT;

    // stage w (o-parity swizzle), coalesced
    const float4* wg = reinterpret_cast<const float4*>(w) + (size_t)n0 * 320;
    #pragma unroll
    for (int jj = 0; jj < 8; ++jj) {
        const int j   = t + jj * 160;        // 0..1279
        const int row = j / 320;
        const int lin = j - row * 320;
        const int o   = lin >> 5;
        const int rem = lin & 31;
        const int i   = rem >> 2;
        const int kh  = rem & 3;
        wl4[row][(o << 5) | ((i ^ (o & 1)) << 2) | kh] = wg[j];
    }
    // stage x (linear, coalesced): 256 float4
    const float4* xg = reinterpret_cast<const float4*>(x);
    {
        int j = t;
        xl4[j] = xg[((size_t)(b0 + (j >> 3)) * NIN + n0) * 2 + (j & 7)];
        j = t + 160;
        if (j < BT * 8)
            xl4[j] = xg[((size_t)(b0 + (j >> 3)) * NIN + n0) * 2 + (j & 7)];
    }
    __syncthreads();

    const int nl = t / 40;              // 0..3
    const int r  = t - nl * 40;
    const int hh = r / 20;              // 0..1: which 16-b half
    const int s  = r - hh * 20;         // 0..19
    const int o  = s >> 1;
    const int k8 = s & 1;
    const int p  = o & 1;
    const float4* wbase = &wl4[nl][(o << 5) | (k8 << 1)];
    const float4* xbase = &xl4[(hh * 16) * 8 + nl * 2];
    unsigned short* ub = u + ((size_t)(b0 + hh * 16) * NIN + n0 + nl) * ROW
                           + o * OL + k8 * 8;
    const size_t ustride = (size_t)NIN * ROW;

    for (int bl = 0; bl < 16; bl += 4) {
        float xv[4][IL];
        #pragma unroll
        for (int bb = 0; bb < 4; ++bb) {
            const float4 x0 = xbase[(bl + bb) * 8];
            const float4 x1 = xbase[(bl + bb) * 8 + 1];
            xv[bb][0] = x0.x; xv[bb][1] = x0.y; xv[bb][2] = x0.z; xv[bb][3] = x0.w;
            xv[bb][4] = x1.x; xv[bb][5] = x1.y; xv[bb][6] = x1.z; xv[bb][7] = x1.w;
        }

        float acc[4][8];
        #pragma unroll
        for (int bb = 0; bb < 4; ++bb)
            #pragma unroll
            for (int j = 0; j < 8; ++j) acc[bb][j] = 0.f;

        #pragma unroll
        for (int i = 0; i < IL; ++i) {
            const float4 wlo = wbase[(i ^ p) << 2];
            const float4 whi = wbase[((i ^ p) << 2) | 1];
            const float wv[8] = {wlo.x, wlo.y, wlo.z, wlo.w, whi.x, whi.y, whi.z, whi.w};
            #pragma unroll
            for (int bb = 0; bb < 4; ++bb)
                #pragma unroll
                for (int j = 0; j < 8; ++j)
                    acc[bb][j] = fmaf(wv[j], xv[bb][i], acc[bb][j]);
        }

        #pragma unroll
        for (int bb = 0; bb < 4; ++bb) {
            union { ushx8 v; __hip_bfloat162 h[4]; } pk;
            #pragma unroll
            for (int j = 0; j < 4; ++j)
                pk.h[j] = __float22bfloat162_rn(make_float2(acc[bb][2*j], acc[bb][2*j+1]));
            *reinterpret_cast<ushx8*>(ub + (size_t)(bl + bb) * ustride) = pk.v;
        }
    }
}

// K2: all 3 routing iterations fused, one block per b. EXACT round-8 code
// (768 thr = 12 waves, 80 VGPR, no spill — r12/r13 showed any added live
// state spills to scratch). Groups of 4 lanes; lane q owns row chunks
// {q+4j} (16B = 8 bf16 of one o); 6 m-steps of 192 n.
__global__ __launch_bounds__(768) void caps_route3(
    const unsigned short* __restrict__ u, const float* __restrict__ bias,
    float* __restrict__ outv)
{
    __shared__ float lds[12][ROW];
    __shared__ float vbuf[ROW];
    const int t  = threadIdx.x;
    const int q  = t & 3;
    const int g  = t >> 2;     // 0..191
    const int wv = t >> 6;     // 0..11
    const int b  = blockIdx.x;
    const unsigned short* ub = u + (size_t)b * NIN * ROW;

    float bsv = 0.f;
    if (t < ROW) bsv = bias[t];
    float vprev = 0.f;

    #pragma unroll
    for (int iter = 0; iter < 3; ++iter) {
        float sp[5][8];
        #pragma unroll
        for (int j = 0; j < 5; ++j)
            #pragma unroll
            for (int e = 0; e < 8; ++e) sp[j][e] = 0.f;

        if (iter == 0) {
            for (int m = 0; m < 6; ++m) {
                const unsigned short* un = ub + (size_t)(g + m * 192) * ROW;
                #pragma unroll
                for (int j = 0; j < 5; ++j) {
                    const ushx8 raw = *reinterpret_cast<const ushx8*>(un + (q + 4 * j) * 8);
                    #pragma unroll
                    for (int e = 0; e < 8; ++e) sp[j][e] += bf2f(raw[e]);
                }
            }
        } else {
            float vs[5][8];
            #pragma unroll
            for (int j = 0; j < 5; ++j) {
                #pragma unroll
                for (int e = 0; e < 8; ++e) vs[j][e] = vbuf[(q + 4 * j) * 8 + e];
            }

            for (int m = 0; m < 6; ++m) {
                const unsigned short* un = ub + (size_t)(g + m * 192) * ROW;
                float uf[5][8];
                #pragma unroll
                for (int j = 0; j < 5; ++j) {
                    const ushx8 raw = *reinterpret_cast<const ushx8*>(un + (q + 4 * j) * 8);
                    #pragma unroll
                    for (int e = 0; e < 8; ++e) uf[j][e] = bf2f(raw[e]);
                }

                // own-parity dots (half-k), combine halves, then swap parity
                float d[5], dd[5];
                #pragma unroll
                for (int j = 0; j < 5; ++j) {
                    float acc = uf[j][0] * vs[j][0];
                    #pragma unroll
                    for (int e = 1; e < 8; ++e) acc = fmaf(uf[j][e], vs[j][e], acc);
                    acc += __shfl_xor(acc, 1, 4);   // h=0 + h=1 -> full 16-k dot
                    d[j] = acc;
                }
                #pragma unroll
                for (int j = 0; j < 5; ++j) dd[j] = __shfl_xor(d[j], 2, 4);

                float mx = fmaxf(d[0], dd[0]);
                #pragma unroll
                for (int j = 1; j < 5; ++j) mx = fmaxf(mx, fmaxf(d[j], dd[j]));
                float se = 0.f, e_[5];
                #pragma unroll
                for (int j = 0; j < 5; ++j) {
                    e_[j] = __expf(d[j] - mx);
                    se += e_[j] + __expf(dd[j] - mx);
                }
                const float r = 1.f / se;
                #pragma unroll
                for (int j = 0; j < 5; ++j) {
                    const float c = e_[j] * r;
                    #pragma unroll
                    for (int e = 0; e < 8; ++e)
                        sp[j][e] = fmaf(c, uf[j][e], sp[j][e]);
                }
            }
        }

        // butterfly over the 16 groups of each wave (masks preserve q)
        #pragma unroll
        for (int j = 0; j < 5; ++j)
            #pragma unroll
            for (int e = 0; e < 8; ++e) {
                #pragma unroll
                for (int msk = 4; msk <= 32; msk <<= 1)
                    sp[j][e] += __shfl_xor(sp[j][e], msk);
            }
        if ((t & 63) < 4) {
            #pragma unroll
            for (int j = 0; j < 5; ++j)
                #pragma unroll
                for (int e = 0; e < 8; ++e)
                    lds[wv][(q + 4 * j) * 8 + e] = sp[j][e];
        }
        __syncthreads();

        if (t < ROW) {
            float ssum = 0.f;
            #pragma unroll
            for (int wvi = 0; wvi < 12; ++wvi) ssum += lds[wvi][t];
            const float sv = (iter == 0 ? 0.1f : 1.0f) * ssum + bsv;

            float dq = sv * sv;
            dq += __shfl_xor(dq, 1, 16);
            dq += __shfl_xor(dq, 2, 16);
            dq += __shfl_xor(dq, 4, 16);
            dq += __shfl_xor(dq, 8, 16);
            const float f = dq / ((1.f + dq) * sqrtf(dq + EPSQ));
            const float v = f * sv;

            if (iter == 0) { vbuf[t] = v; vprev = v; }
            else if (iter == 1) { vbuf[t] = v + vprev; }
            else { outv[(size_t)b * ROW + t] = v; }
        }
        __syncthreads();
    }
}

extern "C" void kernel_launch(void* const* d_in, const int* in_sizes, int n_in,
                              void* d_out, int out_size, void* d_ws, size_t ws_size,
                              hipStream_t stream) {
    const float* x    = (const float*)d_in[0]; // (B, NIN, 8, 1)
    const float* w    = (const float*)d_in[1]; // (1, NIN, O, 8, 16)
    const float* bias = (const float*)d_in[2]; // (1, 1, O, 16, 1)
    float* out = (float*)d_out;                // (B, 1, O, 16, 1)

    unsigned short* u = (unsigned short*)d_ws; // BB*NIN*ROW bf16 = 94.4 MB

    caps_build<<<dim3(NIN / NT, BB / BT), 160, 0, stream>>>(x, w, u);
    caps_route3<<<BB, 768, 0, stream>>>(u, bias, out);
}